// Round 2
// baseline (88.833 us; speedup 1.0000x reference)
//
#include <hip/hip_runtime.h>

// Problem constants (match reference)
#define PB 8          // batches
#define PS 2048       // sequence length
#define PN 4096       // spans per batch
#define PD 256        // feature dim (f32) -> 64 float4 per row
// MAX_W = 16 -> width in [0,15], count = width+1 in [1,16]
// setup guarantees start in [0, S-MAX_W) so rows start..start+15 are in bounds.

// True vector type so __builtin_nontemporal_store accepts it.
typedef float f4 __attribute__((ext_vector_type(4)));

// One wave (64 lanes) per span; lane i owns float4 [4i,4i+4) of D=256.
// Block = 256 threads = 4 spans. Grid = 8192 blocks.
//
// XCD-aware swizzle: batch = blockIdx % 8 keeps each XCD's gathers inside one
// batch's 2 MiB seq slice (fits the 4 MiB per-XCD L2). Output stores are
// non-temporal so the 33.5 MB write stream doesn't evict seq from L2.
//
// Latency structure: two batches of 8 independent f4 loads each, all issued
// before the first dependent use -> 2 memory round-trips per wave (vs ~5 in
// the rolled loop). width/start are scalarized (readfirstlane); masks are
// scalar 0/1 floats feeding v_fmac; the width>=8 branch is wave-uniform.
__global__ __launch_bounds__(256, 8) void span_mean_kernel(
    const float* __restrict__ seq,     // (B, S, D) f32
    const int*   __restrict__ spans,   // (B, N, 2) i32: start, end
    float*       __restrict__ out)     // (B, N, D) f32
{
    const int b       = blockIdx.x & 7;          // batch == XCD (round-robin)
    const int blk     = blockIdx.x >> 3;         // 0..1023 within batch
    const int span_ib = (blk << 2) | (threadIdx.x >> 6);   // 0..4095 in batch
    const int span    = (b << 12) | span_ib;     // global span id
    const int lane    = threadIdx.x & 63;

    // start/end for this span (wave-uniform -> scalarize)
    const int2 se    = ((const int2*)spans)[span];
    const int  start = __builtin_amdgcn_readfirstlane(se.x);
    const int  width = __builtin_amdgcn_readfirstlane(se.y - se.x);  // 0..15

    const float inv = 1.0f / (float)(width + 1);

    const f4* b4 = (const f4*)(seq + (((size_t)b * PS + (size_t)start) * PD)) + lane;

    // ---- batch 1: rows 0..7, unconditional, 8 loads in flight ----
    f4 v[8];
#pragma unroll
    for (int r = 0; r < 8; ++r) v[r] = b4[r * 64];

    f4 acc = v[0];                      // row 0 always included (width >= 0)
#pragma unroll
    for (int r = 1; r < 8; ++r) {
        const float m = (width >= r) ? 1.0f : 0.0f;
        acc += v[r] * m;
    }

    // ---- batch 2: rows 8..15, only when needed (wave-uniform branch) ----
    if (width >= 8) {
        f4 u[8];
#pragma unroll
        for (int r = 0; r < 8; ++r) u[r] = b4[(8 + r) * 64];

        acc += u[0];                    // row 8 always included in this branch
#pragma unroll
        for (int r = 1; r < 8; ++r) {
            const float m = (width >= 8 + r) ? 1.0f : 0.0f;
            acc += u[r] * m;
        }
    }

    acc *= inv;

    // Non-temporal store: keep the 33.5 MB output stream out of L2 so seq
    // stays resident for the gathers.
    f4* outp = (f4*)(out + (size_t)span * PD) + lane;
    __builtin_nontemporal_store(acc, outp);
}

extern "C" void kernel_launch(void* const* d_in, const int* in_sizes, int n_in,
                              void* d_out, int out_size, void* d_ws, size_t ws_size,
                              hipStream_t stream) {
    const float* seq   = (const float*)d_in[0];   // (B,S,D) f32
    const int*   spans = (const int*)d_in[1];     // (B,N,2) i32
    float*       out   = (float*)d_out;           // (B,N,D) f32

    const int n_spans = PB * PN;                  // 32768
    dim3 grid(n_spans / 4);                       // 8192 blocks, 4 spans each
    dim3 block(256);
    span_mean_kernel<<<grid, block, 0, stream>>>(seq, spans, out);
}

// Round 3
// 87.093 us; speedup vs baseline: 1.0200x; 1.0200x over previous
//
#include <hip/hip_runtime.h>

// Problem constants (match reference)
#define PB 8          // batches
#define PS 2048       // sequence length
#define PN 4096       // spans per batch
#define PD 256        // feature dim (f32) -> 64 float4 per row
#define CHUNK 32      // prefix chunk; MAX_W=16 <= CHUNK so a span straddles <=1 boundary
#define NCH (PS / CHUNK)   // 64 chunks per batch
// MAX_W = 16 -> width in [0,15]; start in [0, S-MAX_W) -> rows start..end in bounds.

typedef float f4 __attribute__((ext_vector_type(4)));

// ---------------------------------------------------------------------------
// Kernel A: chunk-local inclusive prefix along S, plus per-chunk totals.
// grid = PB*NCH blocks; b = blockIdx&7 so XCD b produces batch b's P slice
// (2 MiB -> resident in that XCD's 4 MiB L2 for the span kernel's gathers).
// seq is read with non-temporal loads (streamed once, don't cache).
// ---------------------------------------------------------------------------
__global__ __launch_bounds__(256) void chunk_prefix_kernel(
    const float* __restrict__ seq,  // (B, S, D) f32
    float*       __restrict__ P,    // (B, S, D) f32 chunk-local inclusive prefix
    float*       __restrict__ T)    // (B, NCH, D) f32 chunk totals
{
    const int b = blockIdx.x & 7;         // batch == XCD
    const int c = blockIdx.x >> 3;        // chunk 0..NCH-1
    const int d = threadIdx.x;            // 0..255 feature

    const size_t base = ((size_t)b * PS + (size_t)c * CHUNK) * PD + (size_t)d;
    const float* sp = seq + base;
    float*       pp = P   + base;

    float run = 0.0f;
#pragma unroll
    for (int s = 0; s < CHUNK; ++s) {
        run += __builtin_nontemporal_load(sp + (size_t)s * PD);
        pp[(size_t)s * PD] = run;
    }
    T[((size_t)b * NCH + c) * PD + (size_t)d] = run;
}

// ---------------------------------------------------------------------------
// Kernel D: one wave per span; lane i owns float4 [4i,4i+4) of D=256.
// sum(rows start..end) = P[end] - m0*P[start-1] + mt*T[chunk(start-1)]
//   m0 = (start>0), mt = (chunk(end) > chunk(start-1)); start==0 => both 0.
// 3 x 1KB row loads per span (T row is L2/L1-hot: only 64 rows per batch)
// vs avg 9.5 row loads in the direct-gather version.
// ---------------------------------------------------------------------------
__global__ __launch_bounds__(256) void span_mean_kernel(
    const float* __restrict__ P,       // (B, S, D)
    const float* __restrict__ T,       // (B, NCH, D)
    const int*   __restrict__ spans,   // (B, N, 2) i32: start, end (inclusive)
    float*       __restrict__ out)     // (B, N, D) f32
{
    const int b       = blockIdx.x & 7;          // batch == XCD
    const int blk     = blockIdx.x >> 3;         // 0..1023 within batch
    const int span_ib = (blk << 2) | (threadIdx.x >> 6);   // 0..4095 in batch
    const int span    = (b << 12) | span_ib;     // global span id
    const int lane    = threadIdx.x & 63;

    // start/end for this span (wave-uniform -> scalarize)
    const int2 se    = ((const int2*)spans)[span];
    const int  start = __builtin_amdgcn_readfirstlane(se.x);
    const int  end   = __builtin_amdgcn_readfirstlane(se.y);   // inclusive last row
    const int  width = end - start;                            // 0..15

    const float inv = 1.0f / (float)(width + 1);

    const int   sm = (start > 0) ? (start - 1) : 0;
    const float m0 = (start > 0) ? 1.0f : 0.0f;
    const int   cs = sm >> 5;                    // CHUNK = 32
    const int   ce = end >> 5;
    const float mt = (ce > cs) ? 1.0f : 0.0f;    // start==0 => ce==cs==0 => 0

    const f4* Pb = (const f4*)(P + (size_t)b * PS * PD) + lane;
    const f4 pe = Pb[(size_t)end * 64];
    const f4 ps = Pb[(size_t)sm  * 64];
    const f4 tt = ((const f4*)(T + ((size_t)b * NCH + (size_t)cs) * PD))[lane];

    f4 acc = pe - ps * m0 + tt * mt;
    acc *= inv;

    // Non-temporal store: keep the 33.5 MB output stream out of L2 so P
    // stays resident for the gathers.
    f4* outp = (f4*)(out + (size_t)span * PD) + lane;
    __builtin_nontemporal_store(acc, outp);
}

extern "C" void kernel_launch(void* const* d_in, const int* in_sizes, int n_in,
                              void* d_out, int out_size, void* d_ws, size_t ws_size,
                              hipStream_t stream) {
    const float* seq   = (const float*)d_in[0];   // (B,S,D) f32
    const int*   spans = (const int*)d_in[1];     // (B,N,2) i32
    float*       out   = (float*)d_out;           // (B,N,D) f32

    // Workspace layout: P (16.8 MB) then T (0.5 MB); ws is 256 MB.
    float* P = (float*)d_ws;
    float* T = P + (size_t)PB * PS * PD;

    chunk_prefix_kernel<<<dim3(PB * NCH), dim3(256), 0, stream>>>(seq, P, T);

    const int n_spans = PB * PN;                  // 32768
    span_mean_kernel<<<dim3(n_spans / 4), dim3(256), 0, stream>>>(P, T, spans, out);
}